// Round 4
// baseline (1063.857 us; speedup 1.0000x reference)
//
#include <hip/hip_runtime.h>

// ---------------------------------------------------------------------------
// KAN 2-layer forward, round 4.
// vs r3: (1) 2 blocks/CU for phase overlap: BM=64, 256-thread blocks (4 waves
// n-major, wave tile 64 x BN/4), split-K=2 -> 512 blocks; r3 had exactly 1
// block/CU and was barrier-serialized (VALUBusy 17%, MfmaUtil 15%, 7100
// cyc/step vs ~3800 phase-sum). (2) XOR-swizzled LDS (slot=c^(r&3), LDT=32):
// r3's stride-40 had 2.9e7 conflicts; r1's XOR family measured 0.
// (3) act codegen slimmed ~230 -> ~84 VALU (shared d_j, fold 1/6 scale).
// (4) GEMM2 writes d_out directly (ldc=229 + col mask); out_reduce deleted.
// ---------------------------------------------------------------------------

typedef short s16x8 __attribute__((ext_vector_type(8)));  // 8 bf16 = 4 VGPRs
typedef float f32x4 __attribute__((ext_vector_type(4)));

__device__ __forceinline__ unsigned pk2(float lo, float hi) {
  // two fp32 -> packed bf16 pair, RNE (inputs finite)
  unsigned a = __float_as_uint(lo), b = __float_as_uint(hi);
  a = a + 0x7fffu + ((a >> 16) & 1u);
  b = b + 0x7fffu + ((b >> 16) & 1u);
  return __builtin_amdgcn_perm(b, a, 0x07060302u);  // {b.hi16, a.hi16}
}

__device__ __forceinline__ unsigned short f2bf(float f) {
  unsigned u = __float_as_uint(f);
  unsigned r = u + 0x7fffu + ((u >> 16) & 1u);
  return (unsigned short)(r >> 16);
}

// silu + 6 cubic B-spline bases (uniform extended grid, u = 1.5x+4.5, knots
// u=0..9). Equivalent to r3's verified recursion with scales folded:
//   b1_j = max(0, 1-|d_{j+1}|),  B2_j = d_j b1_j - d_{j+3} b1_{j+1}  (=2*b2)
//   b3_j = (d_j B2_j - d_{j+4} B2_{j+1}) / 6
__device__ __forceinline__ uint4 kan_act8(float x) {
  float e = __expf(-x);
  float s = x * __builtin_amdgcn_rcpf(1.0f + e);
  float u = fmaf(x, 1.5f, 4.5f);
  float d[10];
#pragma unroll
  for (int j = 0; j < 10; ++j) d[j] = u - (float)j;
  float b1[8];
#pragma unroll
  for (int j = 0; j < 8; ++j) b1[j] = fmaxf(0.0f, 1.0f - fabsf(d[j + 1]));
  float B2[7];
#pragma unroll
  for (int j = 0; j < 7; ++j) B2[j] = d[j] * b1[j] - d[j + 3] * b1[j + 1];
  float b3[6];
#pragma unroll
  for (int j = 0; j < 6; ++j)
    b3[j] = (d[j] * B2[j] - d[j + 4] * B2[j + 1]) * (1.0f / 6.0f);
  uint4 r;
  r.x = pk2(s, b3[0]);
  r.y = pk2(b3[1], b3[2]);
  r.z = pk2(b3[3], b3[4]);
  r.w = pk2(b3[5], 0.0f);
  return r;
}

// Pack weights: Wp[n][i*8+t] bf16; t=0 base_w, t=1..6 spline_w*scaler, t=7 0.
__global__ __launch_bounds__(256) void prep_w(
    const float* __restrict__ base_w, const float* __restrict__ spline_w,
    const float* __restrict__ scaler, short* __restrict__ Wp,
    int F, int Nvalid) {
  int i = blockIdx.x * 256 + threadIdx.x;
  int n = blockIdx.y;
  if (i >= F) return;
  s16x8 v;
#pragma unroll
  for (int k = 0; k < 8; ++k) v[k] = 0;
  if (n < Nvalid) {
    int idx = n * F + i;
    float sc = scaler[idx];
    v[0] = (short)f2bf(base_w[idx]);
#pragma unroll
    for (int k = 0; k < 6; ++k) v[1 + k] = (short)f2bf(spline_w[idx * 6 + k] * sc);
  }
  *(s16x8*)&Wp[((size_t)n * F + i) * 8] = v;
}

// Fused-activation GEMM. BM=64, BN in {512,256}, BK=32 (4 features).
// 256 threads = 4 waves, all in n (wave tile 64 x BN/4; NT = BN/64 n-tiles).
// blockIdx.y = K-part; C -> Cp + y*pstride, row stride ldc, cols < ncols.
// LDS: 16B chunk c of row r at slot c^(r&3), row stride 32 shorts ->
// <=2-way bank aliasing on all b128 reads/writes (free), 0 measured in r1.
template <int BN>
__global__ __launch_bounds__(256, 2) void kan_gemm(
    const float* __restrict__ X, const short* __restrict__ W,
    float* __restrict__ Cp, int F, int span, long long pstride,
    int ldc, int ncols) {
  constexpr int NT = BN / 64;  // n-tiles per wave == B chunk-writes per thread
  __shared__ __align__(16) short As[64 * 32];
  __shared__ __align__(16) short Bs[BN * 32];

  const int t    = threadIdx.x;
  const int lane = t & 63;
  const int w    = t >> 6;
  const int m0   = blockIdx.x * 64;
  const int f0   = blockIdx.y * span;   // feature offset of this K-part
  const int K8   = F * 8;               // W row stride in shorts

  const int wcol = w * (BN / 4);
  const int mrow = lane & 15;
  const int q    = lane >> 4;
  const int qsw  = (q ^ (mrow & 3)) * 8;

  int a_off[4], b_off[NT];
#pragma unroll
  for (int it = 0; it < 4; ++it)
    a_off[it] = (it * 16 + mrow) * 32 + qsw;
#pragma unroll
  for (int jt = 0; jt < NT; ++jt)
    b_off[jt] = (wcol + jt * 16 + mrow) * 32 + qsw;

  // staging: thread -> (row sr, chunk sc); A row sr, B rows sr + 64*j
  const int sr = t >> 2;
  const int sc = t & 3;
  const int aw = sr * 32 + ((sc ^ (sr & 3)) * 8);
  const float* xp = X + (size_t)(m0 + sr) * F + f0 + sc;
  const short* wp = W + (size_t)sr * K8 + (size_t)(f0 + sc) * 8;

  f32x4 acc[4][NT] = {};

  const int ksteps = span >> 2;
  float xv = *xp;
  uint4 wv[NT];
#pragma unroll
  for (int j = 0; j < NT; ++j)
    wv[j] = *(const uint4*)&wp[(size_t)(j * 64) * K8];

  for (int ks = 0; ks < ksteps; ++ks) {
    uint4 av = kan_act8(xv);
    *(uint4*)&As[aw] = av;
#pragma unroll
    for (int j = 0; j < NT; ++j)
      *(uint4*)&Bs[aw + j * 64 * 32] = wv[j];
    __syncthreads();

    if (ks + 1 < ksteps) {
      xv = xp[(ks + 1) * 4];
#pragma unroll
      for (int j = 0; j < NT; ++j)
        wv[j] = *(const uint4*)&wp[(size_t)(j * 64) * K8 + (size_t)(ks + 1) * 32];
    }

    s16x8 af[4], bfr[NT];
#pragma unroll
    for (int it = 0; it < 4; ++it)
      af[it] = *(const s16x8*)&As[a_off[it]];
#pragma unroll
    for (int jt = 0; jt < NT; ++jt)
      bfr[jt] = *(const s16x8*)&Bs[b_off[jt]];
#pragma unroll
    for (int a = 0; a < 4; ++a)
#pragma unroll
      for (int b = 0; b < NT; ++b)
        acc[a][b] = __builtin_amdgcn_mfma_f32_16x16x32_bf16(
            af[a], bfr[b], acc[a][b], 0, 0, 0);
    __syncthreads();
  }

  // C/D layout: col = lane&15, row = quad*4 + reg (verified r1/r3)
  float* cpt = Cp + (size_t)blockIdx.y * (size_t)pstride;
#pragma unroll
  for (int a = 0; a < 4; ++a) {
#pragma unroll
    for (int b = 0; b < NT; ++b) {
      int col = wcol + b * 16 + mrow;
      if (col < ncols) {
#pragma unroll
        for (int r = 0; r < 4; ++r) {
          int row = m0 + a * 16 + q * 4 + r;
          cpt[(size_t)row * ldc + col] = acc[a][b][r];
        }
      }
    }
  }
}

// h = LayerNorm(p0 + p1) over D=512, one wave per row.
__global__ __launch_bounds__(256) void ln_reduce(
    const float* __restrict__ p0, const float* __restrict__ p1,
    float* __restrict__ h, const float* __restrict__ gamma,
    const float* __restrict__ beta, int nparts) {
  int lane = threadIdx.x & 63;
  int wv   = threadIdx.x >> 6;
  int row  = blockIdx.x * 4 + wv;
  size_t base = (size_t)row * 512 + lane * 8;
  f32x4 v0 = *(const f32x4*)(p0 + base);
  f32x4 v1 = *(const f32x4*)(p0 + base + 4);
  if (nparts == 2) {
    f32x4 u0 = *(const f32x4*)(p1 + base);
    f32x4 u1 = *(const f32x4*)(p1 + base + 4);
#pragma unroll
    for (int k = 0; k < 4; ++k) { v0[k] += u0[k]; v1[k] += u1[k]; }
  }
  float s = 0.f, s2 = 0.f;
#pragma unroll
  for (int k = 0; k < 4; ++k) { s += v0[k] + v1[k]; s2 += v0[k]*v0[k] + v1[k]*v1[k]; }
#pragma unroll
  for (int m = 32; m >= 1; m >>= 1) {
    s  += __shfl_xor(s,  m, 64);
    s2 += __shfl_xor(s2, m, 64);
  }
  float mean = s * (1.0f / 512.0f);
  float var  = s2 * (1.0f / 512.0f) - mean * mean;
  float rstd = rsqrtf(var + 1e-5f);
  const f32x4 g0 = *(const f32x4*)(gamma + lane * 8);
  const f32x4 g1 = *(const f32x4*)(gamma + lane * 8 + 4);
  const f32x4 be0 = *(const f32x4*)(beta + lane * 8);
  const f32x4 be1 = *(const f32x4*)(beta + lane * 8 + 4);
#pragma unroll
  for (int k = 0; k < 4; ++k) {
    v0[k] = (v0[k] - mean) * rstd * g0[k] + be0[k];
    v1[k] = (v1[k] - mean) * rstd * g1[k] + be1[k];
  }
  *(f32x4*)(h + base) = v0;
  *(f32x4*)(h + base + 4) = v1;
}

extern "C" void kernel_launch(void* const* d_in, const int* in_sizes, int n_in,
                              void* d_out, int out_size, void* d_ws, size_t ws_size,
                              hipStream_t stream) {
  const float* x         = (const float*)d_in[0];
  const float* base_w1   = (const float*)d_in[1];
  const float* spline_w1 = (const float*)d_in[2];
  const float* scaler1   = (const float*)d_in[3];
  const float* ln_gamma  = (const float*)d_in[4];
  const float* ln_beta   = (const float*)d_in[5];
  const float* base_w2   = (const float*)d_in[6];
  const float* spline_w2 = (const float*)d_in[7];
  const float* scaler2   = (const float*)d_in[8];
  float* out = (float*)d_out;

  const int B = 16384, D_IN = 1280, D_HID = 512, D_OUT = 229;

  // ws layout: W1p | W2p | h | p0 | p1   (~113 MB with parts=2)
  const size_t szW1 = (size_t)D_HID * D_IN * 8 * 2;   // 10,485,760
  const size_t szW2 = (size_t)256 * D_HID * 8 * 2;    //  2,097,152
  const size_t szH  = (size_t)B * D_HID * 4;          // 33,554,432
  const size_t szP  = (size_t)B * 512 * 4;            // 33,554,432 slot
  char* ws = (char*)d_ws;
  short* W1p = (short*)ws;
  short* W2p = (short*)(ws + szW1);
  float* h   = (float*)(ws + szW1 + szW2);
  float* p0  = (float*)(ws + szW1 + szW2 + szH);
  float* p1  = (float*)(ws + szW1 + szW2 + szH + szP);

  const int parts = (ws_size >= szW1 + szW2 + szH + 2 * szP) ? 2 : 1;
  const long long pstride = (long long)(szP / 4);  // elements, = slot size

  prep_w<<<dim3(D_IN / 256, D_HID), 256, 0, stream>>>(
      base_w1, spline_w1, scaler1, W1p, D_IN, D_HID);
  prep_w<<<dim3(D_HID / 256, 256), 256, 0, stream>>>(
      base_w2, spline_w2, scaler2, W2p, D_HID, D_OUT);

  // layer 1: (16384 x 1280) -> partials (16384 x 512) x parts
  kan_gemm<512><<<dim3(B / 64, parts), 256, 0, stream>>>(
      x, W1p, p0, D_IN, D_IN / parts, pstride, D_HID, D_HID);

  ln_reduce<<<dim3(B / 4), 256, 0, stream>>>(p0, p1, h, ln_gamma, ln_beta, parts);

  // layer 2: (16384 x 512) -> (16384 x 229) straight into d_out
  kan_gemm<256><<<dim3(B / 64, 1), 256, 0, stream>>>(
      h, W2p, out, D_HID, D_HID, 0, D_OUT, D_OUT);
}

// Round 5
// 466.415 us; speedup vs baseline: 2.2809x; 2.2809x over previous
//
#include <hip/hip_runtime.h>

// ---------------------------------------------------------------------------
// KAN 2-layer forward, round 5.
// vs r4 (which spilled: WRITE_SIZE 922 MB vs 67 real; acc128+wv32+act > 256
// cap; everything idle at 9%):
//  (1) B staged via global_load_lds (async, 0 VGPRs). DMA lane->LDS mapping
//      is linear, so the bank swizzle is BAKED INTO the packed W layout in
//      HBM (chunk f stored at position f^(n&3)); A keeps explicit XOR.
//  (2) BN=512 full width (act computed exactly once), BM=128, 512 thr,
//      8 waves 2m x 4n, wave tile 64x128, acc[4][8]=128 AGPR + ~110 arch fits.
//  (3) LDS double-buffered, ONE barrier per K-step: DMA(k+1)+xload ->
//      MFMA(k) -> act(k+1) -> barrier. vmcnt drain hides under ~600cyc of work.
//  split-K=2 -> 256 blocks (1/CU). GEMM2 = same template at BN=256.
// ---------------------------------------------------------------------------

typedef short s16x8 __attribute__((ext_vector_type(8)));  // 8 bf16 = 4 VGPRs
typedef float f32x4 __attribute__((ext_vector_type(4)));

__device__ __forceinline__ void dma16(const void* g, void* l) {
  __builtin_amdgcn_global_load_lds(
      (const __attribute__((address_space(1))) unsigned int*)g,
      (__attribute__((address_space(3))) unsigned int*)l, 16, 0, 0);
}

__device__ __forceinline__ unsigned pk2(float lo, float hi) {
  unsigned a = __float_as_uint(lo), b = __float_as_uint(hi);
  a = a + 0x7fffu + ((a >> 16) & 1u);
  b = b + 0x7fffu + ((b >> 16) & 1u);
  return __builtin_amdgcn_perm(b, a, 0x07060302u);  // {b.hi16, a.hi16}
}

__device__ __forceinline__ unsigned short f2bf(float f) {
  unsigned u = __float_as_uint(f);
  unsigned r = u + 0x7fffu + ((u >> 16) & 1u);
  return (unsigned short)(r >> 16);
}

// silu + 6 cubic B-spline bases (uniform extended grid, u = 1.5x+4.5, knots
// u=0..9; recursion ref-verified r1/r3/r4). Packed bf16x8 [silu,b3_0..5,0].
__device__ __forceinline__ uint4 kan_act8(float x) {
  float e = __expf(-x);
  float s = x * __builtin_amdgcn_rcpf(1.0f + e);
  float u = fmaf(x, 1.5f, 4.5f);
  float d[10];
#pragma unroll
  for (int j = 0; j < 10; ++j) d[j] = u - (float)j;
  float b1[8];
#pragma unroll
  for (int j = 0; j < 8; ++j) b1[j] = fmaxf(0.0f, 1.0f - fabsf(d[j + 1]));
  float B2[7];
#pragma unroll
  for (int j = 0; j < 7; ++j) B2[j] = d[j] * b1[j] - d[j + 3] * b1[j + 1];
  float b3[6];
#pragma unroll
  for (int j = 0; j < 6; ++j)
    b3[j] = (d[j] * B2[j] - d[j + 4] * B2[j + 1]) * (1.0f / 6.0f);
  uint4 r;
  r.x = pk2(s, b3[0]);
  r.y = pk2(b3[1], b3[2]);
  r.z = pk2(b3[3], b3[4]);
  r.w = pk2(b3[5], 0.0f);
  return r;
}

// Pack weights with the bank swizzle baked in: feature i of row n is stored
// at chunk position p = (i & ~3) | ((i & 3) ^ (n & 3)).  t=0 base_w,
// t=1..6 spline_w*scaler, t=7 zero.  Rows n >= Nvalid are zero.
__global__ __launch_bounds__(256) void prep_w(
    const float* __restrict__ base_w, const float* __restrict__ spline_w,
    const float* __restrict__ scaler, short* __restrict__ Wp,
    int F, int Nvalid) {
  int i = blockIdx.x * 256 + threadIdx.x;
  int n = blockIdx.y;
  if (i >= F) return;
  s16x8 v;
#pragma unroll
  for (int k = 0; k < 8; ++k) v[k] = 0;
  if (n < Nvalid) {
    int idx = n * F + i;
    float sc = scaler[idx];
    v[0] = (short)f2bf(base_w[idx]);
#pragma unroll
    for (int k = 0; k < 6; ++k) v[1 + k] = (short)f2bf(spline_w[idx * 6 + k] * sc);
  }
  int p = (i & ~3) | ((i & 3) ^ (n & 3));
  *(s16x8*)&Wp[((size_t)n * F + p) * 8] = v;
}

// Fused-activation GEMM. BM=128, BN in {512,256}, BK=32 (4 features).
// 512 threads = 8 waves (2m x 4n), wave tile 64 x BN/4. blockIdx.z = K-part.
// LDS: [buf][row][4 chunks of 16B], row stride 32 shorts. A chunk j of row r
// at slot j^(r&3); B arrives linear via DMA but W is pre-swizzled in HBM, so
// both sides read feature q at slot q^(row&3): even 8-lanes-per-bank-quad.
template <int BN>
__global__ __launch_bounds__(512, 2) void kan_gemm(
    const float* __restrict__ X, const short* __restrict__ W,
    float* __restrict__ Cp, int F, int span, long long pstride,
    int ldc, int ncols) {
  constexpr int NT = BN / 64;   // n-tiles per wave
  constexpr int IE = BN / 128;  // DMA issues per wave per step
  __shared__ __align__(16) short As[2][128 * 32];
  __shared__ __align__(16) short Bs[2][BN * 32];

  const int t    = threadIdx.x;
  const int lane = t & 63;
  const int w    = t >> 6;
  const int m0   = blockIdx.x * 128;
  const int f0   = blockIdx.z * span;

  const int wrow = (w >> 2) * 64;
  const int wcol = (w & 3) * (BN / 4);
  const int mrow = lane & 15;
  const int q    = lane >> 4;
  const int qs   = (q ^ (mrow & 3)) * 8;

  int a_off[4], b_off[NT];
#pragma unroll
  for (int it = 0; it < 4; ++it)
    a_off[it] = (wrow + it * 16 + mrow) * 32 + qs;
#pragma unroll
  for (int jt = 0; jt < NT; ++jt)
    b_off[jt] = (wcol + jt * 16 + mrow) * 32 + qs;

  // A staging: one activation per thread per step (128 rows x 4 features)
  const int sr = t >> 2, sj = t & 3;
  const float* xq = X + (size_t)(m0 + sr) * F + f0 + sj;
  const int aw = sr * 32 + ((sj ^ (sr & 3)) * 8);

  // B DMA: wave w covers Bs rows [w*BN/8, +BN/8), 16 rows per issue;
  // lane l -> (row l>>2, chunk l&3), LDS dest = uniform base + lane*16B.
  const int drow = w * (BN / 8) + (lane >> 2);
  const int dchk = lane & 3;
  const char* wg = (const char*)W + ((size_t)drow * F + f0) * 16 +
                   (size_t)dchk * 16;
  const size_t gistr = (size_t)16 * F * 16;  // 16 rows of W, bytes

  f32x4 acc[4][NT] = {};
  const int nsteps = span >> 2;

  // prologue: stage step 0 into buffer 0
  {
    float xv = *xq;
#pragma unroll
    for (int e = 0; e < IE; ++e)
      dma16(wg + e * gistr, &Bs[0][(w * (BN / 8) + e * 16) * 32]);
    uint4 av = kan_act8(xv);
    *(uint4*)&As[0][aw] = av;
  }
  __syncthreads();

  for (int ks = 0; ks < nsteps; ++ks) {
    const int cb = ks & 1, nb = cb ^ 1;
    const bool more = (ks + 1 < nsteps);
    float xn = 0.0f;
    if (more) {
#pragma unroll
      for (int e = 0; e < IE; ++e)
        dma16(wg + (size_t)(ks + 1) * 64 + e * gistr,
              &Bs[nb][(w * (BN / 8) + e * 16) * 32]);
      xn = xq[(size_t)(ks + 1) * 4];
    }

    s16x8 af[4], bfr[NT];
#pragma unroll
    for (int it = 0; it < 4; ++it)
      af[it] = *(const s16x8*)&As[cb][a_off[it]];
#pragma unroll
    for (int jt = 0; jt < NT; ++jt)
      bfr[jt] = *(const s16x8*)&Bs[cb][b_off[jt]];
#pragma unroll
    for (int a = 0; a < 4; ++a)
#pragma unroll
      for (int b = 0; b < NT; ++b)
        acc[a][b] = __builtin_amdgcn_mfma_f32_16x16x32_bf16(
            af[a], bfr[b], acc[a][b], 0, 0, 0);

    if (more) {
      uint4 av = kan_act8(xn);
      *(uint4*)&As[nb][aw] = av;
    }
    __syncthreads();
  }

  // C/D layout: col = lane&15, row = quad*4 + reg (verified r1/r3/r4)
  float* cpt = Cp + (size_t)blockIdx.z * (size_t)pstride;
#pragma unroll
  for (int a = 0; a < 4; ++a) {
#pragma unroll
    for (int b = 0; b < NT; ++b) {
      int col = wcol + b * 16 + mrow;
      if (col < ncols) {
#pragma unroll
        for (int r = 0; r < 4; ++r) {
          int row = m0 + wrow + a * 16 + q * 4 + r;
          cpt[(size_t)row * ldc + col] = acc[a][b][r];
        }
      }
    }
  }
}

// h = LayerNorm(p0 + p1) over D=512, one wave per row.
__global__ __launch_bounds__(256) void ln_reduce(
    const float* __restrict__ p0, const float* __restrict__ p1,
    float* __restrict__ h, const float* __restrict__ gamma,
    const float* __restrict__ beta, int nparts) {
  int lane = threadIdx.x & 63;
  int wv   = threadIdx.x >> 6;
  int row  = blockIdx.x * 4 + wv;
  size_t base = (size_t)row * 512 + lane * 8;
  f32x4 v0 = *(const f32x4*)(p0 + base);
  f32x4 v1 = *(const f32x4*)(p0 + base + 4);
  if (nparts == 2) {
    f32x4 u0 = *(const f32x4*)(p1 + base);
    f32x4 u1 = *(const f32x4*)(p1 + base + 4);
#pragma unroll
    for (int k = 0; k < 4; ++k) { v0[k] += u0[k]; v1[k] += u1[k]; }
  }
  float s = 0.f, s2 = 0.f;
#pragma unroll
  for (int k = 0; k < 4; ++k) { s += v0[k] + v1[k]; s2 += v0[k]*v0[k] + v1[k]*v1[k]; }
#pragma unroll
  for (int m = 32; m >= 1; m >>= 1) {
    s  += __shfl_xor(s,  m, 64);
    s2 += __shfl_xor(s2, m, 64);
  }
  float mean = s * (1.0f / 512.0f);
  float var  = s2 * (1.0f / 512.0f) - mean * mean;
  float rstd = rsqrtf(var + 1e-5f);
  const f32x4 g0 = *(const f32x4*)(gamma + lane * 8);
  const f32x4 g1 = *(const f32x4*)(gamma + lane * 8 + 4);
  const f32x4 be0 = *(const f32x4*)(beta + lane * 8);
  const f32x4 be1 = *(const f32x4*)(beta + lane * 8 + 4);
#pragma unroll
  for (int k = 0; k < 4; ++k) {
    v0[k] = (v0[k] - mean) * rstd * g0[k] + be0[k];
    v1[k] = (v1[k] - mean) * rstd * g1[k] + be1[k];
  }
  *(f32x4*)(h + base) = v0;
  *(f32x4*)(h + base + 4) = v1;
}

// out[b][c<229] = p0[b][c] (+ p1[b][c]) from 256-wide padded partials.
__global__ __launch_bounds__(256) void out_reduce(
    const float* __restrict__ p0, const float* __restrict__ p1,
    float* __restrict__ out, int nparts) {
  int idx = blockIdx.x * 256 + threadIdx.x;
  int row = idx >> 8;
  int c   = idx & 255;
  float v = p0[idx];
  if (nparts == 2) v += p1[idx];
  if (c < 229) out[(size_t)row * 229 + c] = v;
}

extern "C" void kernel_launch(void* const* d_in, const int* in_sizes, int n_in,
                              void* d_out, int out_size, void* d_ws, size_t ws_size,
                              hipStream_t stream) {
  const float* x         = (const float*)d_in[0];
  const float* base_w1   = (const float*)d_in[1];
  const float* spline_w1 = (const float*)d_in[2];
  const float* scaler1   = (const float*)d_in[3];
  const float* ln_gamma  = (const float*)d_in[4];
  const float* ln_beta   = (const float*)d_in[5];
  const float* base_w2   = (const float*)d_in[6];
  const float* spline_w2 = (const float*)d_in[7];
  const float* scaler2   = (const float*)d_in[8];
  float* out = (float*)d_out;

  const int B = 16384, D_IN = 1280, D_HID = 512, D_OUT = 229;

  // ws layout: W1p | W2p | h | p0 | p1   (~113 MB with parts=2)
  const size_t szW1 = (size_t)D_HID * D_IN * 8 * 2;   // 10,485,760
  const size_t szW2 = (size_t)256 * D_HID * 8 * 2;    //  2,097,152
  const size_t szH  = (size_t)B * D_HID * 4;          // 33,554,432
  const size_t szP  = (size_t)B * 512 * 4;            // 33,554,432 slot
  char* ws = (char*)d_ws;
  short* W1p = (short*)ws;
  short* W2p = (short*)(ws + szW1);
  float* h   = (float*)(ws + szW1 + szW2);
  float* p0  = (float*)(ws + szW1 + szW2 + szH);
  float* p1  = (float*)(ws + szW1 + szW2 + szH + szP);

  const int parts = (ws_size >= szW1 + szW2 + szH + 2 * szP) ? 2 : 1;
  const long long pstride = (long long)(szP / 4);  // elements = slot size

  prep_w<<<dim3(D_IN / 256, D_HID), 256, 0, stream>>>(
      base_w1, spline_w1, scaler1, W1p, D_IN, D_HID);
  prep_w<<<dim3(D_HID / 256, 256), 256, 0, stream>>>(
      base_w2, spline_w2, scaler2, W2p, D_HID, D_OUT);

  // layer 1: (16384 x 1280) -> split-K partials (16384 x 512) x parts
  kan_gemm<512><<<dim3(B / 128, 1, parts), 512, 0, stream>>>(
      x, W1p, p0, D_IN, D_IN / parts, pstride, D_HID, D_HID);

  ln_reduce<<<dim3(B / 4), 256, 0, stream>>>(p0, p1, h, ln_gamma, ln_beta, parts);

  // layer 2: (16384 x 512) -> split-K partials (16384 x 256) x parts
  kan_gemm<256><<<dim3(B / 128, 1, parts), 512, 0, stream>>>(
      h, W2p, p0, D_HID, D_HID / parts, pstride, 256, 256);

  out_reduce<<<dim3(B * 256 / 256), 256, 0, stream>>>(p0, p1, out, parts);
}